// Round 4
// baseline (262.526 us; speedup 1.0000x reference)
//
#include <hip/hip_runtime.h>

// Problem constants (match the reference)
constexpr int T      = 4096;
constexpr int N      = 16;
constexpr int C      = 512;
constexpr int NC     = N * C;        // 8192 columns
constexpr int NC4    = NC / 4;       // 2048 float4 columns
constexpr int CH     = 64;           // number of T-chunks
constexpr int L      = T / CH;       // 64 rows per chunk
constexpr int TNC    = T * NC;
constexpr int STRIPS = NC4 / 256;    // 8 column strips of 256 float4-cols

// ---------------------------------------------------------------------------
// K1: per-chunk column sums. grid = CH*NC4/256 = 512 blocks x 256 thr.
// Each thread: one float4 column of one chunk, 64 coalesced independent
// 16B loads (1KB/wave-instr), 4 running sums. -> partial[CH][NC4] (2 MB).
// ---------------------------------------------------------------------------
__global__ __launch_bounds__(256) void pool_k1_sums(
    const float* __restrict__ x, float* __restrict__ partial)
{
    int gid  = blockIdx.x * blockDim.x + threadIdx.x;   // 0 .. CH*NC4-1
    int ch   = gid >> 11;          // / NC4 (2048)
    int col4 = gid & (NC4 - 1);

    const float4* xp = reinterpret_cast<const float4*>(x);
    float4 s = make_float4(0.f, 0.f, 0.f, 0.f);
    int base = ch * L * NC4 + col4;
#pragma unroll 8
    for (int i = 0; i < L; ++i) {
        float4 v = xp[base + i * NC4];
        s.x += v.x; s.y += v.y; s.z += v.z; s.w += v.w;
    }
    reinterpret_cast<float4*>(partial)[ch * NC4 + col4] = s;
}

// ---------------------------------------------------------------------------
// K2: fused spine-reduce + finalize. grid = CH*STRIPS = 512 blocks x 256 thr.
// Block (ch, strip): redundantly sum partial rows 0..ch-1 for its 256
// float4-cols (<=63 rows x 4KB, L2/LLC-hot, unroll-8 for MLP), then stream
// its 64 x-rows: running sum, add cached base, multiply by 1/count, store.
// No runtime-indexed local arrays (would spill to scratch). Last chunk also
// writes new_cached_avg; block 0 writes new_cached_len (as float values —
// the harness reads the whole d_out as float32 and splits it).
// ---------------------------------------------------------------------------
__global__ __launch_bounds__(256) void pool_k2_scan(
    const float* __restrict__ x,
    const float* __restrict__ partial,
    const int* __restrict__ cached_len,
    const float* __restrict__ cached_avg,
    float* __restrict__ out,
    float* __restrict__ out_len,
    float* __restrict__ out_avg)
{
    int blk   = blockIdx.x;            // 0 .. CH*STRIPS-1
    int ch    = blk >> 3;              // / STRIPS
    int strip = blk & (STRIPS - 1);
    int col4  = strip * 256 + threadIdx.x;
    int n     = col4 >> 7;             // (col4*4)/512
    float lenf = (float)cached_len[n];

    // spine: exclusive prefix of chunk sums for this column
    const float4* pp = reinterpret_cast<const float4*>(partial);
    float4 s = make_float4(0.f, 0.f, 0.f, 0.f);
#pragma unroll 8
    for (int j = 0; j < ch; ++j) {     // wave-uniform trip count (<= 63)
        float4 v = pp[j * NC4 + col4];
        s.x += v.x; s.y += v.y; s.z += v.z; s.w += v.w;
    }

    // base = cached_avg * len (added last, matching reference association)
    float4 b = reinterpret_cast<const float4*>(cached_avg)[col4];
    b.x *= lenf; b.y *= lenf; b.z *= lenf; b.w *= lenf;

    const float4* xp = reinterpret_cast<const float4*>(x);
    float4* op = reinterpret_cast<float4*>(out);

    int t0 = ch * L;
    float4 o = make_float4(0.f, 0.f, 0.f, 0.f);
#pragma unroll 8
    for (int i = 0; i < L; ++i) {
        int t = t0 + i;
        float4 v = xp[t * NC4 + col4];
        s.x += v.x; s.y += v.y; s.z += v.z; s.w += v.w;
        // match reference rounding: exact fp32 divide, then multiply
        float r = 1.0f / ((float)(t + 1) + lenf);
        o.x = (s.x + b.x) * r;
        o.y = (s.y + b.y) * r;
        o.z = (s.z + b.z) * r;
        o.w = (s.w + b.w) * r;
        op[t * NC4 + col4] = o;
    }

    if (ch == CH - 1) {
        reinterpret_cast<float4*>(out_avg)[col4] = o;   // new_x[-1]
    }
    if (blk == 0 && threadIdx.x < N) {
        out_len[threadIdx.x] = (float)(cached_len[threadIdx.x] + T);
    }
}

// ---------------------------------------------------------------------------
extern "C" void kernel_launch(void* const* d_in, const int* in_sizes, int n_in,
                              void* d_out, int out_size, void* d_ws, size_t ws_size,
                              hipStream_t stream)
{
    const float* x          = (const float*)d_in[0];
    const int*   cached_len = (const int*)d_in[1];
    const float* cached_avg = (const float*)d_in[2];

    // d_out (ALL float32): new_x (T*N*C) | new_cached_len (N, as float values)
    //                      | new_cached_avg (N*C)
    float* out     = (float*)d_out;
    float* out_len = out + TNC;
    float* out_avg = out + TNC + N;

    float* partial = (float*)d_ws;   // CH*NC floats = 2 MB

    pool_k1_sums<<<CH * NC4 / 256, 256, 0, stream>>>(x, partial);
    pool_k2_scan<<<CH * STRIPS,    256, 0, stream>>>(x, partial, cached_len, cached_avg,
                                                     out, out_len, out_avg);
}